// Round 1
// baseline (1616.577 us; speedup 1.0000x reference)
//
#include <hip/hip_runtime.h>

// ---------------- problem constants ----------------
constexpr int NP        = 1000000;     // number of gaussians
constexpr int FC        = 64;          // feature channels
constexpr int SC        = 16;          // semantic channels
constexpr int SCALE_XYZ = 8388608;     // 512*512*32
constexpr int SCALE_YZ  = 16384;       // 512*32
constexpr int SCALE_Z   = 32;
constexpr int CODE_SPACE = 4 * SCALE_XYZ;        // 33,554,432
constexpr int NWORDS     = CODE_SPACE / 32;      // 1,048,576
constexpr int WORDS_PER_BLOCK = 1024;
constexpr int NBLK       = NWORDS / WORDS_PER_BLOCK; // 1024

// output layout (element offsets into float* d_out)
constexpr int OFF_MU   = 0;
constexpr int OFF_SCL  = 3 * NP;
constexpr int OFF_ROT  = 6 * NP;
constexpr int OFF_FEAT = 10 * NP;
constexpr int OFF_SEM  = 74 * NP;
constexpr int OFF_VOX  = 90 * NP;

// ---------------- kernels ----------------

// per-point voxel code; set presence bit in dense mask
__global__ void k_code(const float* __restrict__ mu, const int* __restrict__ batch,
                       unsigned* __restrict__ mask, int* __restrict__ codes) {
    int i = blockIdx.x * blockDim.x + threadIdx.x;
    if (i >= NP) return;
    float x = mu[i * 3 + 0], y = mu[i * 3 + 1], z = mu[i * 3 + 2];
    // must match XLA bit-exactly: (mu - pc_min) / vox, IEEE fp32 division, floor, int cast
    int ix = (int)floorf((x - (-51.2f)) / 0.2f);
    int iy = (int)floorf((y - (-51.2f)) / 0.2f);
    int iz = (int)floorf((z - (-3.2f)) / 0.2f);
    int code = batch[i] * SCALE_XYZ + iz * SCALE_YZ + iy * SCALE_Z + ix;
    codes[i] = code;
    atomicOr(&mask[(unsigned)code >> 5], 1u << (code & 31));
}

// per-block popcount reduce (1024 words / block)
__global__ void k_reduce(const unsigned* __restrict__ mask, unsigned* __restrict__ blockSums) {
    __shared__ unsigned sh[256];
    int t = threadIdx.x;
    int base = blockIdx.x * WORDS_PER_BLOCK + t * 4;
    unsigned s = 0;
    for (int k = 0; k < 4; k++) s += __popc(mask[base + k]);
    sh[t] = s;
    __syncthreads();
    for (int off = 128; off > 0; off >>= 1) {
        if (t < off) sh[t] += sh[t + off];
        __syncthreads();
    }
    if (t == 0) blockSums[blockIdx.x] = sh[0];
}

// scan 1024 block sums -> exclusive offsets; write total group count M
__global__ void k_scan_blocks(unsigned* __restrict__ blockSums, unsigned* __restrict__ dM) {
    __shared__ unsigned sh[NBLK];
    int t = threadIdx.x;
    unsigned v = blockSums[t];
    sh[t] = v;
    __syncthreads();
    for (int off = 1; off < NBLK; off <<= 1) {
        unsigned add = (t >= off) ? sh[t - off] : 0u;
        __syncthreads();
        sh[t] += add;
        __syncthreads();
    }
    blockSums[t] = sh[t] - v;   // exclusive
    if (t == NBLK - 1) *dM = sh[t];
}

// per-word exclusive popcount offsets
__global__ void k_word_off(const unsigned* __restrict__ mask, const unsigned* __restrict__ blockOff,
                           unsigned* __restrict__ wordOff) {
    __shared__ unsigned sh[256];
    int t = threadIdx.x;
    int base = blockIdx.x * WORDS_PER_BLOCK + t * 4;
    unsigned p[4], s = 0;
    for (int k = 0; k < 4; k++) { p[k] = __popc(mask[base + k]); s += p[k]; }
    sh[t] = s;
    __syncthreads();
    unsigned v = s;
    for (int off = 1; off < 256; off <<= 1) {
        unsigned add = (t >= off) ? sh[t - off] : 0u;
        __syncthreads();
        sh[t] += add;
        __syncthreads();
    }
    unsigned myOff = blockOff[blockIdx.x] + sh[t] - v;   // exclusive for this thread's 4 words
    for (int k = 0; k < 4; k++) { wordOff[base + k] = myOff; myOff += p[k]; }
}

// scatter sorted unique codes: ucode[rank] = code
__global__ void k_scatter(const unsigned* __restrict__ mask, const unsigned* __restrict__ wordOff,
                          int* __restrict__ ucode) {
    int w = blockIdx.x * blockDim.x + threadIdx.x;
    if (w >= NWORDS) return;
    unsigned bits = mask[w];
    unsigned r = wordOff[w];
    int base = w * 32;
    while (bits) {
        int b = __ffs(bits) - 1;
        bits &= bits - 1;
        ucode[r++] = base + b;
    }
}

// per-point: rank (= inv), counts, first-occurrence index, mu/scale sums
__global__ void k_inv(const int* __restrict__ codes, const unsigned* __restrict__ mask,
                      const unsigned* __restrict__ wordOff, int* __restrict__ inv,
                      unsigned* __restrict__ counts, unsigned* __restrict__ refIdx,
                      const float* __restrict__ mu, const float* __restrict__ scl,
                      float* __restrict__ out) {
    int i = blockIdx.x * blockDim.x + threadIdx.x;
    if (i >= NP) return;
    int code = codes[i];
    unsigned w = (unsigned)code >> 5;
    unsigned r = wordOff[w] + __popc(mask[w] & ((1u << (code & 31)) - 1u));
    inv[i] = (int)r;
    atomicAdd(&counts[r], 1u);
    atomicMin(&refIdx[r], (unsigned)i);
    atomicAdd(&out[OFF_MU + r * 3 + 0], mu[i * 3 + 0]);
    atomicAdd(&out[OFF_MU + r * 3 + 1], mu[i * 3 + 1]);
    atomicAdd(&out[OFF_MU + r * 3 + 2], mu[i * 3 + 2]);
    atomicAdd(&out[OFF_SCL + r * 3 + 0], scl[i * 3 + 0]);
    atomicAdd(&out[OFF_SCL + r * 3 + 1], scl[i * 3 + 1]);
    atomicAdd(&out[OFF_SCL + r * 3 + 2], scl[i * 3 + 2]);
}

// channel-parallel segment sum (features / semantic)
template <int W>
__global__ void k_chan_sum(const float* __restrict__ src, const int* __restrict__ inv,
                           float* __restrict__ dst, int total) {
    int e = blockIdx.x * blockDim.x + threadIdx.x;
    if (e >= total) return;
    int i = e / W;
    int c = e - i * W;
    int r = inv[i];
    atomicAdd(&dst[r * W + c], src[e]);
}

// antipodal-aligned quaternion sums
__global__ void k_rot(const float* __restrict__ rot, const int* __restrict__ inv,
                      const unsigned* __restrict__ refIdx, float* __restrict__ out) {
    int i = blockIdx.x * blockDim.x + threadIdx.x;
    if (i >= NP) return;
    int r = inv[i];
    int ri = (int)refIdx[r];
    float4 q  = ((const float4*)rot)[i];
    float4 qr = ((const float4*)rot)[ri];
    float d = q.x * qr.x + q.y * qr.y + q.z * qr.z + q.w * qr.w + 1e-8f;
    float s = (d > 0.f) ? 1.f : ((d < 0.f) ? -1.f : 0.f);
    atomicAdd(&out[OFF_ROT + r * 4 + 0], q.x * s);
    atomicAdd(&out[OFF_ROT + r * 4 + 1], q.y * s);
    atomicAdd(&out[OFF_ROT + r * 4 + 2], q.z * s);
    atomicAdd(&out[OFF_ROT + r * 4 + 3], q.w * s);
}

// divide sums by count (mean); rows >= M stay zero
template <int W>
__global__ void k_div(float* __restrict__ base, const unsigned* __restrict__ counts,
                      const unsigned* __restrict__ dM, int total) {
    int e = blockIdx.x * blockDim.x + threadIdx.x;
    if (e >= total) return;
    int r = e / W;
    if (r >= (int)(*dM)) return;
    base[e] /= (float)counts[r];
}

// quaternion mean + normalize
__global__ void k_rot_fin(float* __restrict__ out, const unsigned* __restrict__ counts,
                          const unsigned* __restrict__ dM) {
    int r = blockIdx.x * blockDim.x + threadIdx.x;
    if (r >= NP) return;
    if (r >= (int)(*dM)) return;   // stays zero
    float4* rp = (float4*)(out + OFF_ROT);
    float4 p = rp[r];
    float c = (float)counts[r];
    p.x /= c; p.y /= c; p.z /= c; p.w /= c;
    float n = sqrtf(p.x * p.x + p.y * p.y + p.z * p.z + p.w * p.w);
    n = fmaxf(n, 1e-12f);
    p.x /= n; p.y /= n; p.z /= n; p.w /= n;
    rp[r] = p;
}

// decode voxel coords; padded rows get (-1, 511, 511, 31) per Python floor/mod on -1
__global__ void k_vox(float* __restrict__ out, const int* __restrict__ ucode,
                      const unsigned* __restrict__ dM) {
    int r = blockIdx.x * blockDim.x + threadIdx.x;
    if (r >= NP) return;
    float4 v;
    if (r < (int)(*dM)) {
        int c = ucode[r];
        int vb = c >> 23;                 // / 8388608 (c >= 0)
        int rem = c & (SCALE_XYZ - 1);
        int vz = rem >> 14;               // / 16384
        rem &= (SCALE_YZ - 1);
        int vy = rem >> 5;                // / 32
        int vx = rem & 31;
        v = make_float4((float)vb, (float)vz, (float)vy, (float)vx);
    } else {
        v = make_float4(-1.f, 511.f, 511.f, 31.f);
    }
    ((float4*)(out + OFF_VOX))[r] = v;
}

// ---------------- launcher ----------------
extern "C" void kernel_launch(void* const* d_in, const int* in_sizes, int n_in,
                              void* d_out, int out_size, void* d_ws, size_t ws_size,
                              hipStream_t stream) {
    const float* mu   = (const float*)d_in[0];
    const float* scl  = (const float*)d_in[1];
    const float* rot  = (const float*)d_in[2];
    const float* feat = (const float*)d_in[3];
    const float* sem  = (const float*)d_in[4];
    const int*   bidx = (const int*)d_in[5];
    float* out = (float*)d_out;

    // workspace layout
    char* w = (char*)d_ws;
    unsigned* mask      = (unsigned*)(w);                        // 4 MB
    unsigned* wordOff   = (unsigned*)(w + (4u << 20));           // 4 MB
    unsigned* blockSums = (unsigned*)(w + (8u << 20));           // 4 KB
    unsigned* dM        = (unsigned*)(w + (8u << 20) + 8192);    // 4 B
    char* w2 = w + (8u << 20) + 65536;
    int*      codes  = (int*)(w2);                               // 4 MB
    int*      inv    = (int*)(w2 + 4000000u);                    // 4 MB
    unsigned* counts = (unsigned*)(w2 + 8000000u);               // 4 MB
    unsigned* refIdx = (unsigned*)(w2 + 12000000u);              // 4 MB
    int*      ucode  = (int*)(w2 + 16000000u);                   // 4 MB

    // zero/init (ws and d_out are poisoned before every call)
    hipMemsetAsync(d_out, 0, (size_t)out_size * sizeof(float), stream);
    hipMemsetAsync(mask, 0, (size_t)NWORDS * 4, stream);
    hipMemsetAsync(counts, 0, (size_t)NP * 4, stream);
    hipMemsetAsync(refIdx, 0xFF, (size_t)NP * 4, stream);        // = UINT_MAX

    const int B = 256;
    int gN = (NP + B - 1) / B;

    k_code<<<gN, B, 0, stream>>>(mu, bidx, mask, codes);
    k_reduce<<<NBLK, B, 0, stream>>>(mask, blockSums);
    k_scan_blocks<<<1, NBLK, 0, stream>>>(blockSums, dM);
    k_word_off<<<NBLK, B, 0, stream>>>(mask, blockSums, wordOff);
    k_scatter<<<NWORDS / B, B, 0, stream>>>(mask, wordOff, ucode);
    k_inv<<<gN, B, 0, stream>>>(codes, mask, wordOff, inv, counts, refIdx, mu, scl, out);
    k_chan_sum<FC><<<(NP * FC + B - 1) / B, B, 0, stream>>>(feat, inv, out + OFF_FEAT, NP * FC);
    k_chan_sum<SC><<<(NP * SC + B - 1) / B, B, 0, stream>>>(sem, inv, out + OFF_SEM, NP * SC);
    k_rot<<<gN, B, 0, stream>>>(rot, inv, refIdx, out);
    k_div<3><<<(NP * 3 + B - 1) / B, B, 0, stream>>>(out + OFF_MU, counts, dM, NP * 3);
    k_div<3><<<(NP * 3 + B - 1) / B, B, 0, stream>>>(out + OFF_SCL, counts, dM, NP * 3);
    k_div<FC><<<(NP * FC + B - 1) / B, B, 0, stream>>>(out + OFF_FEAT, counts, dM, NP * FC);
    k_div<SC><<<(NP * SC + B - 1) / B, B, 0, stream>>>(out + OFF_SEM, counts, dM, NP * SC);
    k_rot_fin<<<gN, B, 0, stream>>>(out, counts, dM);
    k_vox<<<gN, B, 0, stream>>>(out, ucode, dM);
}